// Round 8
// baseline (80.118 us; speedup 1.0000x reference)
//
#include <hip/hip_runtime.h>

#define KK 8
#define CC 16

typedef int   vint4   __attribute__((ext_vector_type(4)));
typedef float vfloat4 __attribute__((ext_vector_type(4)));
typedef unsigned int vuint4 __attribute__((ext_vector_type(4)));

// Record: 20B = 16 x i8 features + meta dword {bf16 inv_r2 | bf16 scale<<16}.
// 3 records per 64B line (60B + 4B pad): a record NEVER straddles a line.
static __device__ __forceinline__ unsigned int rec_base(int p) {
    int grp = p / 3;          // magic-mul
    int lane = p - grp * 3;
    return (unsigned int)grp * 64u + (unsigned int)lane * 20u;
}

static __device__ __forceinline__ unsigned short f32_to_bf16(float x) {
    unsigned int b = __float_as_uint(x);
    unsigned int r = b + 0x7FFFu + ((b >> 16) & 1u);
    return (unsigned short)(r >> 16);
}

// Buffer resource descriptor (raw, stride=0, bounds = bytes).
static __device__ __forceinline__ vint4 make_srsrc(const void* p, unsigned int bytes) {
    union { const void* p; unsigned long long u; } a;
    a.p = p;
    vint4 r;
    r.x = (int)(a.u & 0xFFFFFFFFull);
    r.y = (int)((a.u >> 32) & 0xFFFFull);
    r.z = (int)bytes;
    r.w = 0x00020000;
    return r;
}

// ---- Pass 1 (only prep pass): per-point scale + quantize + pack ----
__global__ void prep_kernel(const float* __restrict__ f,
                            const float* __restrict__ radii,
                            char* __restrict__ tab, int P) {
    int p = blockIdx.x * blockDim.x + threadIdx.x;
    if (p >= P) return;
    float v[CC];
    float am = 1e-20f;
#pragma unroll
    for (int c = 0; c < CC; ++c) {
        v[c] = f[(size_t)c * P + p];
        am = fmaxf(am, fabsf(v[c]));
    }
    unsigned short sc_b = f32_to_bf16(am * (1.0f / 127.0f));
    float s = __uint_as_float((unsigned int)sc_b << 16);
    float qs = 1.0f / s;
    unsigned int w[4];
#pragma unroll
    for (int j = 0; j < 4; ++j) {
        int q0 = __float2int_rn(v[4 * j + 0] * qs); q0 = max(-127, min(127, q0));
        int q1 = __float2int_rn(v[4 * j + 1] * qs); q1 = max(-127, min(127, q1));
        int q2 = __float2int_rn(v[4 * j + 2] * qs); q2 = max(-127, min(127, q2));
        int q3 = __float2int_rn(v[4 * j + 3] * qs); q3 = max(-127, min(127, q3));
        w[j] = ((unsigned int)q0 & 0xFFu) | (((unsigned int)q1 & 0xFFu) << 8) |
               (((unsigned int)q2 & 0xFFu) << 16) | (((unsigned int)q3 & 0xFFu) << 24);
    }
    float r = radii[p];
    unsigned short ir2_b = f32_to_bf16(1.0f / (r * r));
    unsigned int meta = (unsigned int)ir2_b | ((unsigned int)sc_b << 16);
    char* rec = tab + rec_base(p);
    *(unsigned int*)(rec + 0) = w[0];
    *(unsigned int*)(rec + 4) = w[1];
    *(unsigned int*)(rec + 8) = w[2];
    *(unsigned int*)(rec + 12) = w[3];
    *(unsigned int*)(rec + 16) = meta;
}

// ---- Pass 2: render. 2 lanes per pixel; lane h owns channels [8h, 8h+8).
// ONE buffer_load_dwordx4 (sc0 = device scope -> L1 bypass, no L1 line fill)
// per fragment per lane at rec+8h:
//   lane0: bytes 0-15  -> ch0-7
//   lane1: bytes 8-23  -> ch8-15 + meta dword in .z
// All 8 gathers issued back-to-back (MLP=8), one vmcnt(0) drain.
__global__ void render_kernel(const int* __restrict__ idx,
                              const float* __restrict__ dists,
                              const char* __restrict__ tab,
                              unsigned int tab_bytes,
                              float* __restrict__ out, int npix) {
    int tid = blockIdx.x * blockDim.x + threadIdx.x;
    int pix = tid >> 1;
    int h = tid & 1;
    if (pix >= npix) return;

    vint4 srsrc = make_srsrc(tab, tab_bytes);

    const vint4* ip = (const vint4*)(idx + (size_t)pix * KK);
    const vfloat4* dp = (const vfloat4*)(dists + (size_t)pix * KK);
    vint4 i0 = __builtin_nontemporal_load(ip);
    vint4 i1 = __builtin_nontemporal_load(ip + 1);
    vfloat4 dv0 = __builtin_nontemporal_load(dp);
    vfloat4 dv1 = __builtin_nontemporal_load(dp + 1);
    int ids[KK] = {i0.x, i0.y, i0.z, i0.w, i1.x, i1.y, i1.z, i1.w};
    float ds[KK] = {dv0.x, dv0.y, dv0.z, dv0.w, dv1.x, dv1.y, dv1.z, dv1.w};

    unsigned int voff[KK];
    float vld[KK];
#pragma unroll
    for (int k = 0; k < KK; ++k) {
        int id = ids[k];
        int sid = id < 0 ? 0 : id;
        vld[k] = id < 0 ? 0.0f : 1.0f;
        voff[k] = rec_base(sid) + 8u * (unsigned int)h;
    }

    vuint4 pk[KK];
#pragma unroll
    for (int k = 0; k < KK; ++k) {
        asm volatile("buffer_load_dwordx4 %0, %1, %2, 0 offen sc0"
                     : "=v"(pk[k])
                     : "v"(voff[k]), "s"(srsrc));
    }
    asm volatile("s_waitcnt vmcnt(0)" ::: "memory");
    __builtin_amdgcn_sched_barrier(0);

    int mlane = ((tid & 63) | 1);  // odd lane of the pair holds meta in .z

    float a0 = 0.f, a1 = 0.f, a2 = 0.f, a3 = 0.f;
    float a4 = 0.f, a5 = 0.f, a6 = 0.f, a7 = 0.f;
    float T = 1.0f;
#pragma unroll
    for (int k = 0; k < KK; ++k) {
        unsigned int meta = (unsigned int)__shfl((int)pk[k].z, mlane, 64);
        float ir2 = __uint_as_float((meta & 0xFFFFu) << 16);
        float s = __uint_as_float(meta & 0xFFFF0000u);
        float w = (1.0f - ds[k] * ir2) * vld[k];
        float as = (w * T) * s;
        T *= (1.0f - w);
        unsigned int px = pk[k].x, py = pk[k].y;
        a0 += as * (float)((int)(px << 24) >> 24);
        a1 += as * (float)((int)(px << 16) >> 24);
        a2 += as * (float)((int)(px << 8) >> 24);
        a3 += as * (float)((int)px >> 24);
        a4 += as * (float)((int)(py << 24) >> 24);
        a5 += as * (float)((int)(py << 16) >> 24);
        a6 += as * (float)((int)(py << 8) >> 24);
        a7 += as * (float)((int)py >> 24);
    }

    float* ob = out + (size_t)pix * CC + 8 * h;
    vfloat4 r0 = {a0, a1, a2, a3};
    vfloat4 r1 = {a4, a5, a6, a7};
    __builtin_nontemporal_store(r0, (vfloat4*)ob);
    __builtin_nontemporal_store(r1, (vfloat4*)(ob + 4));
}

extern "C" void kernel_launch(void* const* d_in, const int* in_sizes, int n_in,
                              void* d_out, int out_size, void* d_ws, size_t ws_size,
                              hipStream_t stream) {
    const int* idx = (const int*)d_in[0];
    const float* dists = (const float*)d_in[1];
    const float* radii = (const float*)d_in[2];
    const float* features = (const float*)d_in[3];
    float* out = (float*)d_out;

    int P = in_sizes[2];            // 200000
    int npix = in_sizes[0] / KK;    // B*H*W = 1048576

    char* tab = (char*)d_ws;        // ceil(P/3)*64 = ~4.27MB
    unsigned int tab_bytes = (unsigned int)(((P + 2) / 3) * 64);

    prep_kernel<<<(P + 255) / 256, 256, 0, stream>>>(features, radii, tab, P);

    int nthreads = npix * 2;
    render_kernel<<<(nthreads + 255) / 256, 256, 0, stream>>>(
        idx, dists, tab, tab_bytes, out, npix);
}